// Round 8
// baseline (107.387 us; speedup 1.0000x reference)
//
#include <hip/hip_runtime.h>
#include <hip/hip_fp16.h>

// Fast discrete Radon transform (exact, wrap-around shears), radix-16,
// single fused kernel, decoupled A/B chains, fp16 intermediates.
//   case A (m<512):   R_m[t]  = sum_y img[(t - m*y) & 511, y]
//   case B (m>=512):  R'_a[t] = sum_x img[x, (t - 2a*x) & 511], a = m-512
// out = R * (1/sqrt(512)), imag exactly 0.
//
// D_q[c][w][x] = sum_{u<q} A'[u*h+w][(x - c*u*h) & 511],  h = 512/q
// D_{16q}[C][w][x] = sum_{b<16} D_q[C mod q][w + b*H][(x - C*b*H) & 511]
//
// A chain (needs transpose): init(radix-2,1 LDS round) -> radix-16 -> radix-16.
// B chain (no transpose): radix-2 FUSED into first radix-16 (reads img rows
// directly) -> radix-16.  B has its own per-batch barriers (target 16) and
// never waits on A; B compute overlaps A's transpose phase, B exits early.

#define NN 512
#define MU 768
#define MASK 511
#define SCALE 0.04419417382415922f  // 1/sqrt(512)
#define NB 768

typedef float v4f __attribute__((ext_vector_type(4)));  // nontemporal-store-able

union H8 { float4 f4; __half2 h2[4]; };
union H4 { float2 f2; __half2 h2[2]; };

// Producer: flush writes, bump counter (device scope).
__device__ __forceinline__ void bar_signal(unsigned* cnt) {
  __syncthreads();
  if (threadIdx.x == 0) {
    __threadfence();
    atomicAdd(cnt, 1u);
  }
}
// Consumer: spin until `target` producers arrived. Deadlock-free: every
// block signals before it waits, all NB blocks co-resident (3/CU, checked
// at launch via hipOccupancyMaxActiveBlocksPerMultiprocessor).
__device__ __forceinline__ void bar_wait(unsigned* cnt, unsigned target) {
  if (threadIdx.x == 0) {
    while (__atomic_load_n(cnt, __ATOMIC_ACQUIRE) < target)
      __builtin_amdgcn_s_sleep(8);
    __threadfence();   // invalidate stale cached lines before reading
  }
  __syncthreads();
}

__global__ __launch_bounds__(512, 6) void drt_fused(
    const float* __restrict__ img, float2* __restrict__ out,
    __half* __restrict__ A0, __half* __restrict__ A1,
    __half* __restrict__ B1, unsigned* __restrict__ bar) {
  // A-init: 3 x 64x65 fp32 tiles (49.9 KB -> still 3 blocks/CU);
  // passes: 16x512 fp32 (32 KB) aliased on the same allocation.
  __shared__ float LDS[12480];
  const int bid = blockIdx.x;
  const int t = threadIdx.x;
  unsigned* barA  = bar;        // [16], target 32
  unsigned* barA2 = bar + 16;   // [16], target 32
  unsigned* barB  = bar + 32;   // [16], target 16

  if (bid < 512) {
    // =================== A chain: 32 blocks per batch ====================
    const int b = bid >> 5, idx = bid & 31;

    // ---- P0: transpose + radix-2, single LDS round ----
    {
      const int xt = idx & 7, wt = idx >> 3;
      const int x0 = xt * 64, w0 = wt * 64, x3 = ((xt + 4) & 7) * 64;
      const float* src = img + (size_t)b * NN * NN;
      float* T1 = LDS;           // [64][65]
      float* T2 = LDS + 4160;
      float* T3 = LDS + 8320;
      for (int i = t; i < 4096; i += 512) {
        int rr = i >> 6, cc = i & 63;
        T1[rr * 65 + cc] = src[(x0 + rr) * NN + w0 + cc];
        T2[rr * 65 + cc] = src[(x0 + rr) * NN + w0 + 256 + cc];
        T3[rr * 65 + cc] = src[(x3 + rr) * NN + w0 + 256 + cc];
      }
      __syncthreads();
      __half2* d = (__half2*)A0 + (size_t)b * 512 * 256;
      for (int i = t; i < 2048; i += 512) {
        int wl = i >> 5, xp = i & 31;
        float t1a = T1[(2 * xp) * 65 + wl], t1b = T1[(2 * xp + 1) * 65 + wl];
        float a0 = t1a + T2[(2 * xp) * 65 + wl];
        float a1 = t1b + T2[(2 * xp + 1) * 65 + wl];
        d[(w0 + wl) * 256 + (x0 >> 1) + xp] = __float22half2_rn(make_float2(a0, a1));
        float b0 = t1a + T3[(2 * xp) * 65 + wl];
        float b1 = t1b + T3[(2 * xp + 1) * 65 + wl];
        d[(256 + w0 + wl) * 256 + (x0 >> 1) + xp] = __float22half2_rn(make_float2(b0, b1));
      }
    }

    bar_signal(&barA[b]);
    bar_wait(&barA[b], 32u);

    // ---- P1: stage 2 -> 32 (H=16), unit (c = idx>>4, w = idx&15) ----
    {
      const int c = idx >> 4, w = idx & 15;
      float* L = LDS;
      const float4* s4 = (const float4*)(A0 + (size_t)b * 512 * NN);
      const int pbase = c * 256 + w;
      for (int it = 0; it < 2; ++it) {
        int flat = it * 512 + t;  // 1024 chunks of 8 halves
        int lrow = flat >> 6, ch = flat & 63;
        H8 u; u.f4 = s4[(size_t)(pbase + 16 * lrow) * 64 + ch];
        float2 p0 = __half22float2(u.h2[0]), p1 = __half22float2(u.h2[1]);
        float2 p2 = __half22float2(u.h2[2]), p3 = __half22float2(u.h2[3]);
        float4* l4 = (float4*)&L[lrow * 512 + ch * 8];
        l4[0] = make_float4(p0.x, p0.y, p1.x, p1.y);
        l4[1] = make_float4(p2.x, p2.y, p3.x, p3.y);
      }
      __syncthreads();
      const int g = t >> 7;
      const int x4 = (t & 127) * 4;
      float2* op = (float2*)(A1 + (size_t)b * 512 * NN);
      for (int jj = 0; jj < 4; ++jj) {
        const int j = jj * 4 + g;
        const int C = c + 2 * j;
        float4 acc = {0.f, 0.f, 0.f, 0.f};
#pragma unroll
        for (int bb = 0; bb < 16; ++bb) {
          int base = (x4 - C * bb * 16) & MASK;  // %4==0: aligned, no wrap
          float4 v = *(const float4*)&L[bb * 512 + base];
          acc.x += v.x; acc.y += v.y; acc.z += v.z; acc.w += v.w;
        }
        H4 h;
        h.h2[0] = __float22half2_rn(make_float2(acc.x, acc.y));
        h.h2[1] = __float22half2_rn(make_float2(acc.z, acc.w));
        op[(C * 16 + w) * 128 + (x4 >> 2)] = h.f2;
      }
    }

    bar_signal(&barA2[b]);
    bar_wait(&barA2[b], 32u);

    // ---- P2: stage 32 -> 512 (H=1), rotated staging, fused out ----
    {
      const int c = idx;  // stage-32 class 0..31
      const __half2* i2 = (const __half2*)(A1 + (size_t)b * 512 * NN +
                                           (size_t)c * 16 * NN);
      float* L = LDS;
      for (int it = 0; it < 8; ++it) {
        int flat = it * 512 + t;
        int bb = flat >> 8, p = flat & 255;
        float2 f = __half22float2(i2[bb * 256 + p]);
        int y0 = (2 * p + c * bb) & MASK;     // row bb rotated by c*bb
        L[bb * 512 + y0] = f.x;
        L[bb * 512 + ((y0 + 1) & MASK)] = f.y;
      }
      __syncthreads();
      const int g = t >> 7;
      const int xq = (t & 127) << 2;
      float4 acc[4];
#pragma unroll
      for (int jj = 0; jj < 4; ++jj) acc[jj] = {0.f, 0.f, 0.f, 0.f};
#pragma unroll
      for (int bb = 0; bb < 16; ++bb) {
        const float* row = L + bb * 512;
        int base = (xq - 128 * g * bb) & MASK;  // shift 32*j*bb, j=4g
        const int step = (32 * bb) & MASK;
#pragma unroll
        for (int jj = 0; jj < 4; ++jj) {
          float4 v = *(const float4*)&row[base];  // aligned, wrap-free
          acc[jj].x += v.x; acc[jj].y += v.y; acc[jj].z += v.z; acc[jj].w += v.w;
          base = (base - step) & MASK;
        }
      }
#pragma unroll
      for (int jj = 0; jj < 4; ++jj) {
        const int j = 4 * g + jj;
        const int m = c + 32 * j;
        v4f o1 = {acc[jj].x * SCALE, 0.f, acc[jj].y * SCALE, 0.f};
        v4f o2 = {acc[jj].z * SCALE, 0.f, acc[jj].w * SCALE, 0.f};
        v4f* op = (v4f*)(out + ((size_t)b * MU + m) * NN + xq);
        __builtin_nontemporal_store(o1, op);
        __builtin_nontemporal_store(o2, op + 1);
      }
    }
  } else {
    // =================== B chain: 16 blocks per batch ====================
    const int v = bid - 512, b = v >> 4, w = v & 15;

    // ---- P0: radix-2 (from img rows) FUSED with stage 2 -> 32 ----
    {
      float* L = LDS;
      const float4* s4 = (const float4*)(img + (size_t)b * NN * NN);
      for (int it = 0; it < 4; ++it) {
        int flat = it * 512 + t;  // 2048 float4 = 16 rows x 128
        int lrow = flat >> 7, col = flat & 127;
        float4 u = s4[(w + 16 * lrow) * 128 + col];
        float4 z = s4[(w + 16 * lrow + 256) * 128 + col];
        u.x += z.x; u.y += z.y; u.z += z.z; u.w += z.w;
        *(float4*)&L[lrow * 512 + col * 4] = u;
      }
      __syncthreads();
      const int g = t >> 7;
      const int x4 = (t & 127) * 4;
      float2* op = (float2*)(B1 + (size_t)b * 256 * NN);
      for (int jj = 0; jj < 4; ++jj) {
        const int j = jj * 4 + g;
        const int C = 2 * j;
        float4 acc = {0.f, 0.f, 0.f, 0.f};
#pragma unroll
        for (int bb = 0; bb < 16; ++bb) {
          int base = (x4 - C * bb * 16) & MASK;
          float4 vv = *(const float4*)&L[bb * 512 + base];
          acc.x += vv.x; acc.y += vv.y; acc.z += vv.z; acc.w += vv.w;
        }
        H4 h;
        h.h2[0] = __float22half2_rn(make_float2(acc.x, acc.y));
        h.h2[1] = __float22half2_rn(make_float2(acc.z, acc.w));
        op[(j * 16 + w) * 128 + (x4 >> 2)] = h.f2;
      }
    }

    bar_signal(&barB[b]);
    bar_wait(&barB[b], 16u);

    // ---- P1: stage 32 -> 512, rotated staging, fused out; then exit ----
    {
      const int a = w;             // B1 slab 0..15, class c = 2a
      const int c = 2 * a;
      const __half2* i2 = (const __half2*)(B1 + (size_t)b * 256 * NN +
                                           (size_t)a * 16 * NN);
      float* L = LDS;
      for (int it = 0; it < 8; ++it) {
        int flat = it * 512 + t;
        int bb = flat >> 8, p = flat & 255;
        float2 f = __half22float2(i2[bb * 256 + p]);
        int y0 = (2 * p + c * bb) & MASK;
        L[bb * 512 + y0] = f.x;
        L[bb * 512 + ((y0 + 1) & MASK)] = f.y;
      }
      __syncthreads();
      const int g = t >> 7;
      const int xq = (t & 127) << 2;
      float4 acc[4];
#pragma unroll
      for (int jj = 0; jj < 4; ++jj) acc[jj] = {0.f, 0.f, 0.f, 0.f};
#pragma unroll
      for (int bb = 0; bb < 16; ++bb) {
        const float* row = L + bb * 512;
        int base = (xq - 128 * g * bb) & MASK;
        const int step = (32 * bb) & MASK;
#pragma unroll
        for (int jj = 0; jj < 4; ++jj) {
          float4 vv = *(const float4*)&row[base];
          acc[jj].x += vv.x; acc[jj].y += vv.y; acc[jj].z += vv.z; acc[jj].w += vv.w;
          base = (base - step) & MASK;
        }
      }
#pragma unroll
      for (int jj = 0; jj < 4; ++jj) {
        const int j = 4 * g + jj;
        const int m = 512 + a + 16 * j;
        v4f o1 = {acc[jj].x * SCALE, 0.f, acc[jj].y * SCALE, 0.f};
        v4f o2 = {acc[jj].z * SCALE, 0.f, acc[jj].w * SCALE, 0.f};
        v4f* op = (v4f*)(out + ((size_t)b * MU + m) * NN + xq);
        __builtin_nontemporal_store(o1, op);
        __builtin_nontemporal_store(o2, op + 1);
      }
    }
  }
}

// ============ fallback path: 3 separate fp32 kernels (round-3/4) ==========
__global__ __launch_bounds__(256) void k_init(const float* __restrict__ img,
                                              float* __restrict__ A0,
                                              float* __restrict__ B0) {
  const int bx = blockIdx.x, b = blockIdx.y;
  const float* src = img + (size_t)b * NN * NN;
  if (bx < 32) {
    __shared__ float T1[64][65], T2[64][65], T3[64][65];
    const int xt = bx & 7, wt = bx >> 3;
    const int x0 = xt * 64, w0 = wt * 64, x3 = ((xt + 4) & 7) * 64;
    for (int idx = threadIdx.x; idx < 4096; idx += 256) {
      int rr = idx >> 6, cc = idx & 63;
      T1[rr][cc] = src[(x0 + rr) * NN + w0 + cc];
      T2[rr][cc] = src[(x0 + rr) * NN + w0 + 256 + cc];
      T3[rr][cc] = src[(x3 + rr) * NN + w0 + 256 + cc];
    }
    __syncthreads();
    float* dst = A0 + (size_t)b * (512 * NN);
    for (int idx = threadIdx.x; idx < 4096; idx += 256) {
      int wl = idx >> 6, xl = idx & 63;
      float t1 = T1[xl][wl];
      dst[(size_t)(w0 + wl) * NN + x0 + xl]       = t1 + T2[xl][wl];
      dst[(size_t)(256 + w0 + wl) * NN + x0 + xl] = t1 + T3[xl][wl];
    }
  } else {
    const int w0 = (bx - 32) * 32;
    const float4* s4 = (const float4*)src;
    float4* d4 = (float4*)(B0 + (size_t)b * (256 * NN));
    for (int it = 0; it < 16; ++it) {
      int flat = it * 256 + threadIdx.x;
      int row = w0 + (flat >> 7), col = flat & 127;
      float4 u = s4[row * 128 + col], v = s4[(row + 256) * 128 + col];
      u.x += v.x; u.y += v.y; u.z += v.z; u.w += v.w;
      d4[row * 128 + col] = u;
    }
  }
}

__global__ __launch_bounds__(512) void k_pass1(const float* __restrict__ A0,
                                               const float* __restrict__ B0,
                                               float* __restrict__ A1,
                                               float* __restrict__ B1) {
  __shared__ float L[16 * 512];
  const int bx = blockIdx.x, b = blockIdx.y;
  const int t = threadIdx.x;
  const bool isB = bx >= 32;
  const int c = isB ? 0 : (bx >> 4);
  const int w = isB ? (bx - 32) : (bx & 15);
  const float* in = isB ? (B0 + (size_t)b * 256 * NN) : (A0 + (size_t)b * 512 * NN);
  {
    const float4* s4 = (const float4*)in;
    float4* l4 = (float4*)L;
    const int pbase = c * 256 + w;
    for (int it = 0; it < 4; ++it) {
      int flat = it * 512 + t;
      int lrow = flat >> 7, col = flat & 127;
      l4[lrow * 128 + col] = s4[(pbase + 16 * lrow) * 128 + col];
    }
  }
  __syncthreads();
  const int g = t >> 7;
  const int x4 = (t & 127) * 4;
  float* outA = A1 + (size_t)b * 512 * NN;
  float* outB = B1 + (size_t)b * 256 * NN;
  for (int jj = 0; jj < 4; ++jj) {
    const int j = jj * 4 + g;
    const int C = isB ? (2 * j) : (c + 2 * j);
    float4 acc = {0.f, 0.f, 0.f, 0.f};
#pragma unroll
    for (int bb = 0; bb < 16; ++bb) {
      int base = (x4 - C * bb * 16) & MASK;
      float4 v = *(const float4*)&L[bb * 512 + base];
      acc.x += v.x; acc.y += v.y; acc.z += v.z; acc.w += v.w;
    }
    const int orow = isB ? (j * 16 + w) : (C * 16 + w);
    float* op = isB ? outB : outA;
    *(float4*)&op[(size_t)orow * NN + x4] = acc;
  }
}

__global__ __launch_bounds__(512) void k_pass2(const float* __restrict__ A1,
                                               const float* __restrict__ B1,
                                               float2* __restrict__ out) {
  __shared__ float L[16 * 512];
  const int bx = blockIdx.x, b = blockIdx.y;
  const int t = threadIdx.x;
  const bool isB = bx >= 32;
  const int c = isB ? 2 * (bx - 32) : bx;
  const float* in = isB ? (B1 + (size_t)b * 256 * NN + (size_t)(bx - 32) * 16 * NN)
                        : (A1 + (size_t)b * 512 * NN + (size_t)c * 16 * NN);
#pragma unroll
  for (int bb = 0; bb < 16; ++bb) {
    float v = in[bb * 512 + t];
    L[bb * 512 + ((t + c * bb) & MASK)] = v;
  }
  __syncthreads();
  const int g = t >> 7;
  const int xq = (t & 127) << 2;
  float4 acc[4];
#pragma unroll
  for (int jj = 0; jj < 4; ++jj) acc[jj] = {0.f, 0.f, 0.f, 0.f};
#pragma unroll
  for (int bb = 0; bb < 16; ++bb) {
    const float* row = L + bb * 512;
    int base = (xq - 128 * g * bb) & MASK;
    const int step = (32 * bb) & MASK;
#pragma unroll
    for (int jj = 0; jj < 4; ++jj) {
      float4 v = *(const float4*)&row[base];
      acc[jj].x += v.x; acc[jj].y += v.y; acc[jj].z += v.z; acc[jj].w += v.w;
      base = (base - step) & MASK;
    }
  }
#pragma unroll
  for (int jj = 0; jj < 4; ++jj) {
    const int j = 4 * g + jj;
    const int m = isB ? (512 + (bx - 32) + 16 * j) : (c + 32 * j);
    float2* op = out + ((size_t)b * MU + m) * NN + xq;
    float4 a = acc[jj];
    op[0] = {a.x * SCALE, 0.f};
    op[1] = {a.y * SCALE, 0.f};
    op[2] = {a.z * SCALE, 0.f};
    op[3] = {a.w * SCALE, 0.f};
  }
}

extern "C" void kernel_launch(void* const* d_in, const int* in_sizes, int n_in,
                              void* d_out, int out_size, void* d_ws, size_t ws_size,
                              hipStream_t stream) {
  const float* img = (const float*)d_in[0];

  int maxb = 0;
  (void)hipOccupancyMaxActiveBlocksPerMultiprocessor(&maxb, (const void*)drt_fused,
                                                     512, 0);
  const bool can_fuse = (maxb >= 3) && (ws_size >= (size_t)(20971520 + 192));

  if (can_fuse) {
    char* W = (char*)d_ws;
    __half* A0 = (__half*)(W);              // 16 x 512 x 512 fp16
    __half* A1 = (__half*)(W + 8388608);    // 16 x 512 x 512 fp16
    __half* B1 = (__half*)(W + 16777216);   // 16 x 256 x 512 fp16
    unsigned* bar = (unsigned*)(W + 20971520);  // 48 per-batch counters
    (void)hipMemsetAsync(bar, 0, 192, stream);
    drt_fused<<<dim3(NB), dim3(512), 0, stream>>>(img, (float2*)d_out,
                                                  A0, A1, B1, bar);
  } else if (ws_size >= (size_t)51 * 1024 * 1024) {
    float* W  = (float*)d_ws;
    float* A0 = W;
    float* A1 = W + 4194304;
    float* B0 = W + 8388608;
    float* B1 = W + 10485760;
    k_init <<<dim3(40, 16), dim3(256), 0, stream>>>(img, A0, B0);
    k_pass1<<<dim3(48, 16), dim3(512), 0, stream>>>(A0, B0, A1, B1);
    k_pass2<<<dim3(48, 16), dim3(512), 0, stream>>>(A1, B1, (float2*)d_out);
  }
}